// Round 1
// baseline (708.278 us; speedup 1.0000x reference)
//
#include <hip/hip_runtime.h>
#include <math.h>

#define B_   64
#define L_   500
#define F_   256
#define H_   4
#define DK   64
#define RT   24    // attention row tile
#define CT   512   // attention col tile (padded from 500)

// ---------------------------------------------------------------------------
// Kernel 1: head projections  qh = q @ w_qs, vh = v @ w_vs
// out layout: [B, H, L, dk]  (row index bh = b*4+h)
// grid (500, 2), block 256. Tile: 64 rows x 256 cols, 8x8 per thread.
// ---------------------------------------------------------------------------
__global__ __launch_bounds__(256) void proj_kernel(
    const float* __restrict__ q, const float* __restrict__ v,
    const float* __restrict__ wq, const float* __restrict__ wv,
    float* __restrict__ qh, float* __restrict__ vh)
{
    const int which = blockIdx.y;
    const float* __restrict__ x = which ? v : q;
    const float* __restrict__ w = which ? wv : wq;
    float* __restrict__ o = which ? vh : qh;

    __shared__ float At[32][68];    // [k][m], padded
    __shared__ float Bs[32][260];   // [k][n], padded

    const int tid  = threadIdx.x;
    const int row0 = blockIdx.x * 64;
    const int rq = tid >> 5;        // 0..7 -> rows rq*8..rq*8+7
    const int cq = tid & 31;        // 0..31 -> cols cq*8..cq*8+7

    float acc[8][8];
    #pragma unroll
    for (int i = 0; i < 8; i++)
        #pragma unroll
        for (int j = 0; j < 8; j++) acc[i][j] = 0.f;

    for (int kc = 0; kc < 256; kc += 32) {
        // A tile 64 rows x 32 k -> transposed into At[k][m]
        #pragma unroll
        for (int it = 0; it < 2; it++) {
            int flat = tid + it * 256;          // 0..511
            int m  = flat >> 3;                 // 0..63
            int k4 = flat & 7;                  // 0..7
            float4 a = *(const float4*)&x[(row0 + m) * 256 + kc + k4 * 4];
            At[k4*4+0][m] = a.x; At[k4*4+1][m] = a.y;
            At[k4*4+2][m] = a.z; At[k4*4+3][m] = a.w;
        }
        // B tile 32 k x 256 n (contiguous in w)
        #pragma unroll
        for (int it = 0; it < 8; it++) {
            int flat = tid + it * 256;          // f4 index 0..2047
            int k  = flat >> 6;
            int n4 = flat & 63;
            *(float4*)&Bs[k][n4*4] = *(const float4*)&w[(kc + k) * 256 + n4 * 4];
        }
        __syncthreads();
        #pragma unroll 4
        for (int k = 0; k < 32; k++) {
            float4 a0 = *(const float4*)&At[k][rq*8];
            float4 a1 = *(const float4*)&At[k][rq*8+4];
            float4 b0 = *(const float4*)&Bs[k][cq*8];
            float4 b1 = *(const float4*)&Bs[k][cq*8+4];
            float av[8] = {a0.x,a0.y,a0.z,a0.w,a1.x,a1.y,a1.z,a1.w};
            float bv[8] = {b0.x,b0.y,b0.z,b0.w,b1.x,b1.y,b1.z,b1.w};
            #pragma unroll
            for (int i = 0; i < 8; i++)
                #pragma unroll
                for (int j = 0; j < 8; j++)
                    acc[i][j] = fmaf(av[i], bv[j], acc[i][j]);
        }
        __syncthreads();
    }

    // epilogue: scatter to [B,H,L,dk]
    const int h  = cq >> 3;
    const int d0 = (cq & 7) * 8;
    #pragma unroll
    for (int i = 0; i < 8; i++) {
        int m = row0 + rq * 8 + i;
        int b = m / 500;
        int l = m - b * 500;
        float* dst = &o[((b * 4 + h) * 500 + l) * 64 + d0];
        *(float4*)dst       = make_float4(acc[i][0], acc[i][1], acc[i][2], acc[i][3]);
        *(float4*)(dst + 4) = make_float4(acc[i][4], acc[i][5], acc[i][6], acc[i][7]);
    }
}

// ---------------------------------------------------------------------------
// Kernel 2: dense-synthesizer attention, fused per (b,h) x 24-row tile
// ctx[b,l,h*64+d] = softmax(relu(qh w1 + b1) w2 + b2) @ vh
// grid (21, 256), block 256 (4 waves).
// ---------------------------------------------------------------------------
__global__ __launch_bounds__(256) void attn_kernel(
    const float* __restrict__ qh, const float* __restrict__ vh,
    const float* __restrict__ w1, const float* __restrict__ b1,
    const float* __restrict__ w2, const float* __restrict__ b2,
    float* __restrict__ ctx)
{
    __shared__ float q_s[RT * 64];     // 6 KB
    __shared__ float s_s[RT * 64];     // 6 KB
    __shared__ float attn[RT * CT];    // 48 KB

    const int tid = threadIdx.x;
    const int bh  = blockIdx.y;            // b*4 + h
    const int l0  = blockIdx.x * RT;
    const int nrows = min(RT, L_ - l0);
    const int wv = tid >> 6;               // wave 0..3
    const int ln = tid & 63;               // lane

    // P1: load q rows (contiguous) into LDS
    const float* qsrc = &qh[(bh * 500 + l0) * 64];
    for (int i = tid; i < nrows * 16; i += 256)
        *(float4*)&q_s[i * 4] = *(const float4*)&qsrc[i * 4];
    __syncthreads();

    // P2: s = relu(q @ w1 + b1); lane = d, wave -> 6 rows
    {
        float a[6] = {0,0,0,0,0,0};
        for (int k = 0; k < 64; k++) {
            float wk = w1[k * 64 + ln];
            #pragma unroll
            for (int i = 0; i < 6; i++)
                a[i] = fmaf(q_s[(wv * 6 + i) * 64 + k], wk, a[i]);
        }
        float bb = b1[ln];
        #pragma unroll
        for (int i = 0; i < 6; i++)
            s_s[(wv * 6 + i) * 64 + ln] = fmaxf(a[i] + bb, 0.f);
    }
    __syncthreads();

    // P3: logits = s @ w2 + b2 -> attn[24][512] (c>=500 -> -inf)
    {
        float a[6][8];
        #pragma unroll
        for (int i = 0; i < 6; i++)
            #pragma unroll
            for (int j = 0; j < 8; j++) a[i][j] = 0.f;
        for (int k = 0; k < 64; k++) {
            float w2v[8];
            #pragma unroll
            for (int j = 0; j < 8; j++) {
                int c = ln + 64 * j;
                w2v[j] = (c < 500) ? w2[k * 500 + c] : 0.f;
            }
            float sv[6];
            #pragma unroll
            for (int i = 0; i < 6; i++) sv[i] = s_s[(wv * 6 + i) * 64 + k];
            #pragma unroll
            for (int i = 0; i < 6; i++)
                #pragma unroll
                for (int j = 0; j < 8; j++)
                    a[i][j] = fmaf(sv[i], w2v[j], a[i][j]);
        }
        #pragma unroll
        for (int j = 0; j < 8; j++) {
            int c = ln + 64 * j;
            float bb = (c < 500) ? b2[c] : 0.f;
            #pragma unroll
            for (int i = 0; i < 6; i++)
                attn[(wv * 6 + i) * CT + c] = (c < 500) ? (a[i][j] + bb)
                                                        : -INFINITY;
        }
    }
    __syncthreads();

    // P4: softmax per row (wave handles 6 rows)
    for (int rr = 0; rr < 6; rr++) {
        int r = wv * 6 + rr;
        float vv[8];
        #pragma unroll
        for (int j = 0; j < 8; j++) vv[j] = attn[r * CT + ln + 64 * j];
        float m = vv[0];
        #pragma unroll
        for (int j = 1; j < 8; j++) m = fmaxf(m, vv[j]);
        #pragma unroll
        for (int off = 32; off; off >>= 1) m = fmaxf(m, __shfl_xor(m, off));
        float s = 0.f;
        #pragma unroll
        for (int j = 0; j < 8; j++) { vv[j] = __expf(vv[j] - m); s += vv[j]; }
        #pragma unroll
        for (int off = 32; off; off >>= 1) s += __shfl_xor(s, off);
        float inv = 1.f / s;
        #pragma unroll
        for (int j = 0; j < 8; j++) attn[r * CT + ln + 64 * j] = vv[j] * inv;
    }
    __syncthreads();

    // P5: out = p @ vh ; columns split across waves (128/128/128/116)
    const float* vsrc = &vh[bh * 500 * 64];
    float oacc[RT];
    #pragma unroll
    for (int r = 0; r < RT; r++) oacc[r] = 0.f;
    const int c0   = wv * 128;
    const int cend = min(500, c0 + 128);
    for (int c4 = c0; c4 < cend; c4 += 4) {
        float vv[4];
        #pragma unroll
        for (int u = 0; u < 4; u++) vv[u] = vsrc[(c4 + u) * 64 + ln];
        #pragma unroll
        for (int r = 0; r < RT; r++) {
            float4 p4 = *(const float4*)&attn[r * CT + c4];
            oacc[r] += p4.x * vv[0] + p4.y * vv[1] + p4.z * vv[2] + p4.w * vv[3];
        }
    }
    __syncthreads();

    // cross-wave reduction via q_s/s_s, wave 0 writes ctx
    if (wv == 2) { for (int r = 0; r < RT; r++) q_s[r * 64 + ln] = oacc[r]; }
    if (wv == 3) { for (int r = 0; r < RT; r++) s_s[r * 64 + ln] = oacc[r]; }
    __syncthreads();
    if (wv == 0) { for (int r = 0; r < RT; r++) oacc[r] += q_s[r * 64 + ln]; }
    if (wv == 1) { for (int r = 0; r < RT; r++) oacc[r] += s_s[r * 64 + ln]; }
    __syncthreads();
    if (wv == 1) { for (int r = 0; r < RT; r++) q_s[r * 64 + ln] = oacc[r]; }
    __syncthreads();
    if (wv == 0) {
        const int b = bh >> 2, h = bh & 3;
        for (int r = 0; r < nrows; r++) {
            float val = oacc[r] + q_s[r * 64 + ln];
            ctx[(b * 500 + l0 + r) * 256 + h * 64 + ln] = val;
        }
    }
}

// ---------------------------------------------------------------------------
// Kernel 3: out = LayerNorm(ctx @ fc_w + q) * g + b
// grid (500), block 256. Tile: 64 rows x 256 cols, 8x8 per thread.
// ---------------------------------------------------------------------------
__global__ __launch_bounds__(256) void final_kernel(
    const float* __restrict__ ctx, const float* __restrict__ fcw,
    const float* __restrict__ qres, const float* __restrict__ g,
    const float* __restrict__ bta, float* __restrict__ out)
{
    __shared__ float At[32][68];
    __shared__ float Bs[32][260];

    const int tid  = threadIdx.x;
    const int row0 = blockIdx.x * 64;
    const int rq = tid >> 5;
    const int cq = tid & 31;

    float acc[8][8];
    #pragma unroll
    for (int i = 0; i < 8; i++)
        #pragma unroll
        for (int j = 0; j < 8; j++) acc[i][j] = 0.f;

    for (int kc = 0; kc < 256; kc += 32) {
        #pragma unroll
        for (int it = 0; it < 2; it++) {
            int flat = tid + it * 256;
            int m  = flat >> 3;
            int k4 = flat & 7;
            float4 a = *(const float4*)&ctx[(row0 + m) * 256 + kc + k4 * 4];
            At[k4*4+0][m] = a.x; At[k4*4+1][m] = a.y;
            At[k4*4+2][m] = a.z; At[k4*4+3][m] = a.w;
        }
        #pragma unroll
        for (int it = 0; it < 8; it++) {
            int flat = tid + it * 256;
            int k  = flat >> 6;
            int n4 = flat & 63;
            *(float4*)&Bs[k][n4*4] = *(const float4*)&fcw[(kc + k) * 256 + n4 * 4];
        }
        __syncthreads();
        #pragma unroll 4
        for (int k = 0; k < 32; k++) {
            float4 a0 = *(const float4*)&At[k][rq*8];
            float4 a1 = *(const float4*)&At[k][rq*8+4];
            float4 b0 = *(const float4*)&Bs[k][cq*8];
            float4 b1 = *(const float4*)&Bs[k][cq*8+4];
            float av[8] = {a0.x,a0.y,a0.z,a0.w,a1.x,a1.y,a1.z,a1.w};
            float bv[8] = {b0.x,b0.y,b0.z,b0.w,b1.x,b1.y,b1.z,b1.w};
            #pragma unroll
            for (int i = 0; i < 8; i++)
                #pragma unroll
                for (int j = 0; j < 8; j++)
                    acc[i][j] = fmaf(av[i], bv[j], acc[i][j]);
        }
        __syncthreads();
    }

    // epilogue: +residual, LayerNorm over 256 cols (32 threads share a row)
    float gv[8], bv8[8];
    #pragma unroll
    for (int j = 0; j < 8; j++) { gv[j] = g[cq*8+j]; bv8[j] = bta[cq*8+j]; }
    #pragma unroll
    for (int i = 0; i < 8; i++) {
        int m = row0 + rq * 8 + i;
        float4 r0 = *(const float4*)&qres[m * 256 + cq * 8];
        float4 r1 = *(const float4*)&qres[m * 256 + cq * 8 + 4];
        float vals[8] = {acc[i][0]+r0.x, acc[i][1]+r0.y, acc[i][2]+r0.z, acc[i][3]+r0.w,
                         acc[i][4]+r1.x, acc[i][5]+r1.y, acc[i][6]+r1.z, acc[i][7]+r1.w};
        float s = 0.f, s2 = 0.f;
        #pragma unroll
        for (int j = 0; j < 8; j++) { s += vals[j]; s2 += vals[j] * vals[j]; }
        #pragma unroll
        for (int off = 16; off; off >>= 1) {
            s  += __shfl_xor(s,  off);
            s2 += __shfl_xor(s2, off);
        }
        float mu  = s  * 0.00390625f;
        float var = s2 * 0.00390625f - mu * mu;
        float rs  = rsqrtf(var + 1e-6f);
        float o8[8];
        #pragma unroll
        for (int j = 0; j < 8; j++) o8[j] = (vals[j] - mu) * rs * gv[j] + bv8[j];
        *(float4*)&out[m * 256 + cq * 8]     = make_float4(o8[0], o8[1], o8[2], o8[3]);
        *(float4*)&out[m * 256 + cq * 8 + 4] = make_float4(o8[4], o8[5], o8[6], o8[7]);
    }
}

// ---------------------------------------------------------------------------
extern "C" void kernel_launch(void* const* d_in, const int* in_sizes, int n_in,
                              void* d_out, int out_size, void* d_ws, size_t ws_size,
                              hipStream_t stream)
{
    const float* q   = (const float*)d_in[0];
    // d_in[1] = k : unused by the reference
    const float* v   = (const float*)d_in[2];
    const float* wqs = (const float*)d_in[3];
    const float* wvs = (const float*)d_in[4];
    const float* w1  = (const float*)d_in[5];
    const float* b1  = (const float*)d_in[6];
    const float* w2  = (const float*)d_in[7];
    const float* b2  = (const float*)d_in[8];
    const float* fcw = (const float*)d_in[9];
    const float* lng = (const float*)d_in[10];
    const float* lnb = (const float*)d_in[11];
    float* out = (float*)d_out;

    float* ws  = (float*)d_ws;
    float* qh  = ws;                    // [B,H,L,dk]  8,192,000 floats
    float* vh  = ws + 8192000;          // [B,H,L,dk]  8,192,000 floats
    float* ctx = ws + 16384000;         // [B,L,F]     8,192,000 floats

    proj_kernel <<<dim3(500, 2), 256, 0, stream>>>(q, v, wqs, wvs, qh, vh);
    attn_kernel <<<dim3(21, 256), 256, 0, stream>>>(qh, vh, w1, b1, w2, b2, ctx);
    final_kernel<<<dim3(500),    256, 0, stream>>>(ctx, fcw, q, lng, lnb, out);
}

// Round 2
// 406.375 us; speedup vs baseline: 1.7429x; 1.7429x over previous
//
#include <hip/hip_runtime.h>
#include <math.h>

#define B_   64
#define L_   500
#define F_   256
#define H_   4
#define DK   64

typedef unsigned short u16;
typedef unsigned int   u32;
typedef __attribute__((ext_vector_type(8))) short short8;
typedef __attribute__((ext_vector_type(4))) float f32x4;

static __device__ __forceinline__ u16 f2bf(float f) {
    u32 u = __float_as_uint(f);
    u32 r = (u + 0x7FFFu + ((u >> 16) & 1u)) >> 16;
    return (u16)r;
}

// ---------------------------------------------------------------------------
// Prep: w1T[64][64], w2T[512][64] bf16 (n>=500 zero-padded)
// ---------------------------------------------------------------------------
__global__ __launch_bounds__(256) void prep_kernel(
    const float* __restrict__ w1, const float* __restrict__ w2,
    u16* __restrict__ w1T, u16* __restrict__ w2T)
{
    int t = blockIdx.x * 256 + threadIdx.x;
    int stride = gridDim.x * 256;
    for (int i = t; i < 64 * 64; i += stride) {
        int n = i >> 6, k = i & 63;
        w1T[i] = f2bf(w1[k * 64 + n]);
    }
    for (int i = t; i < 512 * 64; i += stride) {
        int n = i >> 6, k = i & 63;
        w2T[i] = f2bf(n < 500 ? w2[k * 500 + n] : 0.f);
    }
}

// ---------------------------------------------------------------------------
// Kernel 1: head projections (fp32 GEMM core, bf16 epilogues)
//  which=0: qh_bf [bh][500][64] bf16
//  which=1: vhT   [bh][64][512] bf16 (transposed; k>=500 pad never read w/ P!=0)
// grid (500, 2), block 256.
// ---------------------------------------------------------------------------
__global__ __launch_bounds__(256) void proj_kernel(
    const float* __restrict__ q, const float* __restrict__ v,
    const float* __restrict__ wq, const float* __restrict__ wv,
    u16* __restrict__ qh_bf, u16* __restrict__ vhT)
{
    const int which = blockIdx.y;
    const float* __restrict__ x = which ? v : q;
    const float* __restrict__ w = which ? wv : wq;

    __shared__ float At[32][68];
    __shared__ float Bs[32][260];

    const int tid  = threadIdx.x;
    const int row0 = blockIdx.x * 64;
    const int rq = tid >> 5;
    const int cq = tid & 31;

    float acc[8][8];
    #pragma unroll
    for (int i = 0; i < 8; i++)
        #pragma unroll
        for (int j = 0; j < 8; j++) acc[i][j] = 0.f;

    for (int kc = 0; kc < 256; kc += 32) {
        #pragma unroll
        for (int it = 0; it < 2; it++) {
            int flat = tid + it * 256;
            int m  = flat >> 3;
            int k4 = flat & 7;
            float4 a = *(const float4*)&x[(row0 + m) * 256 + kc + k4 * 4];
            At[k4*4+0][m] = a.x; At[k4*4+1][m] = a.y;
            At[k4*4+2][m] = a.z; At[k4*4+3][m] = a.w;
        }
        #pragma unroll
        for (int it = 0; it < 8; it++) {
            int flat = tid + it * 256;
            int k  = flat >> 6;
            int n4 = flat & 63;
            *(float4*)&Bs[k][n4*4] = *(const float4*)&w[(kc + k) * 256 + n4 * 4];
        }
        __syncthreads();
        #pragma unroll 4
        for (int k = 0; k < 32; k++) {
            float4 a0 = *(const float4*)&At[k][rq*8];
            float4 a1 = *(const float4*)&At[k][rq*8+4];
            float4 b0 = *(const float4*)&Bs[k][cq*8];
            float4 b1 = *(const float4*)&Bs[k][cq*8+4];
            float av[8] = {a0.x,a0.y,a0.z,a0.w,a1.x,a1.y,a1.z,a1.w};
            float bv[8] = {b0.x,b0.y,b0.z,b0.w,b1.x,b1.y,b1.z,b1.w};
            #pragma unroll
            for (int i = 0; i < 8; i++)
                #pragma unroll
                for (int j = 0; j < 8; j++)
                    acc[i][j] = fmaf(av[i], bv[j], acc[i][j]);
        }
        __syncthreads();
    }

    const int h  = cq >> 3;
    const int d0 = (cq & 7) * 8;
    if (which == 0) {
        // qh bf16, row-major [bh*500+l][64]
        #pragma unroll
        for (int i = 0; i < 8; i++) {
            int m = row0 + rq * 8 + i;
            int b = m / 500;
            int l = m - b * 500;
            __align__(16) u16 t8[8];
            #pragma unroll
            for (int j = 0; j < 8; j++) t8[j] = f2bf(acc[i][j]);
            u16* dst = qh_bf + ((size_t)((b * 4 + h) * 500 + l)) * 64 + d0;
            *(uint4*)dst = *(const uint4*)t8;
        }
    } else {
        // vhT bf16: vhT[(bh*64+d)*512 + l]
        int m0 = row0 + rq * 8;
        int b0 = m0 / 500;
        int b7 = (m0 + 7) / 500;
        if (b0 == b7) {
            int l0 = m0 - b0 * 500;     // multiple of 4 -> 8B aligned
            #pragma unroll
            for (int j = 0; j < 8; j++) {
                __align__(8) u16 t8[8];
                #pragma unroll
                for (int i = 0; i < 8; i++) t8[i] = f2bf(acc[i][j]);
                u16* dst = vhT + ((size_t)((b0 * 4 + h) * 64 + d0 + j)) * 512 + l0;
                *(uint2*)dst       = *(const uint2*)t8;
                *(uint2*)(dst + 4) = *(const uint2*)(t8 + 4);
            }
        } else {
            #pragma unroll
            for (int i = 0; i < 8; i++) {
                int m = m0 + i;
                int b = m / 500;
                int l = m - b * 500;
                #pragma unroll
                for (int j = 0; j < 8; j++)
                    vhT[((size_t)((b * 4 + h) * 64 + d0 + j)) * 512 + l] = f2bf(acc[i][j]);
            }
        }
    }
}

// ---------------------------------------------------------------------------
// Kernel 2: dense-synthesizer attention, bf16 MFMA.
// 1 block = 64 rows of one (b,h); 4 waves x 16-row strips.
// grid (8, 256), block 256.
// ---------------------------------------------------------------------------
__global__ __launch_bounds__(256) void attn_kernel(
    const u16* __restrict__ qh, const u16* __restrict__ vhT,
    const u16* __restrict__ w1T, const float* __restrict__ b1,
    const u16* __restrict__ w2T, const float* __restrict__ b2,
    float* __restrict__ ctx)
{
    __shared__ u16 s_lds[4][16][72];    // s strip, pad 72 el (144 B)
    __shared__ u16 p_lds[4][16][136];   // P chunk, pad 136 el (272 B)
    __shared__ u16 v_lds[64][136];      // vhT chunk [d][k], pad 272 B

    const int tid  = threadIdx.x;
    const int wv   = tid >> 6;
    const int ln   = tid & 63;
    const int n16  = ln & 15;
    const int quad = ln >> 4;
    const int bh   = blockIdx.y;
    const int r0   = blockIdx.x * 64 + wv * 16;   // row base within (b,h)

    // ---- Phase A: s = relu(qh @ w1 + b1), 16 rows per wave ----
    {
        const u16* qbase = qh + ((size_t)(bh * 500 + r0 + n16)) * 64;
        short8 a0 = *(const short8*)(qbase + quad * 8);
        short8 a1 = *(const short8*)(qbase + 32 + quad * 8);
        #pragma unroll
        for (int nt = 0; nt < 4; nt++) {
            const u16* wb = w1T + (nt * 16 + n16) * 64;
            short8 bb0 = *(const short8*)(wb + quad * 8);
            short8 bb1 = *(const short8*)(wb + 32 + quad * 8);
            f32x4 c = {0.f, 0.f, 0.f, 0.f};
            c = __builtin_amdgcn_mfma_f32_16x16x32_bf16(a0, bb0, c, 0, 0, 0);
            c = __builtin_amdgcn_mfma_f32_16x16x32_bf16(a1, bb1, c, 0, 0, 0);
            float bias = b1[nt * 16 + n16];
            #pragma unroll
            for (int i = 0; i < 4; i++)
                s_lds[wv][quad * 4 + i][nt * 16 + n16] = f2bf(fmaxf(c[i] + bias, 0.f));
        }
    }
    __syncthreads();

    // ---- Phase B: logits = s @ w2 + b2 -> acc[32] tiles (fp32), cols padded 512 ----
    f32x4 acc[32];
    {
        short8 sa0 = *(const short8*)&s_lds[wv][n16][quad * 8];
        short8 sa1 = *(const short8*)&s_lds[wv][n16][32 + quad * 8];
        #pragma unroll
        for (int nt = 0; nt < 32; nt++) {
            const u16* wb = w2T + (nt * 16 + n16) * 64;
            short8 bb0 = *(const short8*)(wb + quad * 8);
            short8 bb1 = *(const short8*)(wb + 32 + quad * 8);
            f32x4 c = {0.f, 0.f, 0.f, 0.f};
            c = __builtin_amdgcn_mfma_f32_16x16x32_bf16(sa0, bb0, c, 0, 0, 0);
            c = __builtin_amdgcn_mfma_f32_16x16x32_bf16(sa1, bb1, c, 0, 0, 0);
            int col = nt * 16 + n16;
            float bias = (col < 500) ? b2[col] : -INFINITY;
            #pragma unroll
            for (int i = 0; i < 4; i++) c[i] += bias;
            acc[nt] = c;
        }
    }

    // ---- softmax stats; P left unnormalized (fold 1/sum into PV epilogue) ----
    float inv[4];
    {
        float mx[4], sm[4];
        #pragma unroll
        for (int i = 0; i < 4; i++) mx[i] = acc[0][i];
        #pragma unroll
        for (int nt = 1; nt < 32; nt++)
            #pragma unroll
            for (int i = 0; i < 4; i++) mx[i] = fmaxf(mx[i], acc[nt][i]);
        #pragma unroll
        for (int off = 1; off < 16; off <<= 1)
            #pragma unroll
            for (int i = 0; i < 4; i++) mx[i] = fmaxf(mx[i], __shfl_xor(mx[i], off));
        #pragma unroll
        for (int i = 0; i < 4; i++) sm[i] = 0.f;
        #pragma unroll
        for (int nt = 0; nt < 32; nt++)
            #pragma unroll
            for (int i = 0; i < 4; i++) {
                float e = __expf(acc[nt][i] - mx[i]);
                acc[nt][i] = e;
                sm[i] += e;
            }
        #pragma unroll
        for (int off = 1; off < 16; off <<= 1)
            #pragma unroll
            for (int i = 0; i < 4; i++) sm[i] += __shfl_xor(sm[i], off);
        #pragma unroll
        for (int i = 0; i < 4; i++) inv[i] = 1.f / sm[i];
    }

    // ---- Phase C: out = P @ vh in 4 K-chunks of 128 ----
    f32x4 oacc[4];
    #pragma unroll
    for (int nt = 0; nt < 4; nt++) oacc[nt] = (f32x4){0.f, 0.f, 0.f, 0.f};

    for (int cc = 0; cc < 4; cc++) {
        // stage vhT chunk [64][128] cooperatively
        #pragma unroll
        for (int u = tid; u < 1024; u += 256) {
            int d  = u >> 4;
            int kk = (u & 15) * 8;
            *(short8*)&v_lds[d][kk] =
                *(const short8*)(vhT + ((size_t)(bh * 64 + d)) * 512 + cc * 128 + kk);
        }
        // write this wave's P chunk (col tiles cc*8 .. cc*8+7)
        #pragma unroll
        for (int t = 0; t < 8; t++) {
            int nt = cc * 8 + t;
            int c  = t * 16 + n16;
            #pragma unroll
            for (int i = 0; i < 4; i++)
                p_lds[wv][quad * 4 + i][c] = f2bf(acc[nt][i]);
        }
        __syncthreads();
        #pragma unroll
        for (int ks = 0; ks < 4; ks++) {
            short8 pa = *(const short8*)&p_lds[wv][n16][ks * 32 + quad * 8];
            #pragma unroll
            for (int nt = 0; nt < 4; nt++) {
                short8 vb = *(const short8*)&v_lds[nt * 16 + n16][ks * 32 + quad * 8];
                oacc[nt] = __builtin_amdgcn_mfma_f32_16x16x32_bf16(pa, vb, oacc[nt], 0, 0, 0);
            }
        }
        __syncthreads();
    }

    // ---- epilogue: scale by 1/sum, write ctx fp32 ----
    {
        const int b = bh >> 2, h = bh & 3;
        #pragma unroll
        for (int i = 0; i < 4; i++) {
            int lrow = r0 + quad * 4 + i;
            if (lrow < 500) {
                float s = inv[i];
                float* dst = &ctx[((size_t)(b * 500 + lrow)) * 256 + h * 64];
                #pragma unroll
                for (int nt = 0; nt < 4; nt++)
                    dst[nt * 16 + n16] = oacc[nt][i] * s;
            }
        }
    }
}

// ---------------------------------------------------------------------------
// Kernel 3: out = LayerNorm(ctx @ fc_w + q) (fp32, unchanged)
// ---------------------------------------------------------------------------
__global__ __launch_bounds__(256) void final_kernel(
    const float* __restrict__ ctx, const float* __restrict__ fcw,
    const float* __restrict__ qres, const float* __restrict__ g,
    const float* __restrict__ bta, float* __restrict__ out)
{
    __shared__ float At[32][68];
    __shared__ float Bs[32][260];

    const int tid  = threadIdx.x;
    const int row0 = blockIdx.x * 64;
    const int rq = tid >> 5;
    const int cq = tid & 31;

    float acc[8][8];
    #pragma unroll
    for (int i = 0; i < 8; i++)
        #pragma unroll
        for (int j = 0; j < 8; j++) acc[i][j] = 0.f;

    for (int kc = 0; kc < 256; kc += 32) {
        #pragma unroll
        for (int it = 0; it < 2; it++) {
            int flat = tid + it * 256;
            int m  = flat >> 3;
            int k4 = flat & 7;
            float4 a = *(const float4*)&ctx[(row0 + m) * 256 + kc + k4 * 4];
            At[k4*4+0][m] = a.x; At[k4*4+1][m] = a.y;
            At[k4*4+2][m] = a.z; At[k4*4+3][m] = a.w;
        }
        #pragma unroll
        for (int it = 0; it < 8; it++) {
            int flat = tid + it * 256;
            int k  = flat >> 6;
            int n4 = flat & 63;
            *(float4*)&Bs[k][n4*4] = *(const float4*)&fcw[(kc + k) * 256 + n4 * 4];
        }
        __syncthreads();
        #pragma unroll 4
        for (int k = 0; k < 32; k++) {
            float4 a0 = *(const float4*)&At[k][rq*8];
            float4 a1 = *(const float4*)&At[k][rq*8+4];
            float4 b0 = *(const float4*)&Bs[k][cq*8];
            float4 b1 = *(const float4*)&Bs[k][cq*8+4];
            float av[8] = {a0.x,a0.y,a0.z,a0.w,a1.x,a1.y,a1.z,a1.w};
            float bv[8] = {b0.x,b0.y,b0.z,b0.w,b1.x,b1.y,b1.z,b1.w};
            #pragma unroll
            for (int i = 0; i < 8; i++)
                #pragma unroll
                for (int j = 0; j < 8; j++)
                    acc[i][j] = fmaf(av[i], bv[j], acc[i][j]);
        }
        __syncthreads();
    }

    float gv[8], bv8[8];
    #pragma unroll
    for (int j = 0; j < 8; j++) { gv[j] = g[cq*8+j]; bv8[j] = bta[cq*8+j]; }
    #pragma unroll
    for (int i = 0; i < 8; i++) {
        int m = row0 + rq * 8 + i;
        float4 r0 = *(const float4*)&qres[m * 256 + cq * 8];
        float4 r1 = *(const float4*)&qres[m * 256 + cq * 8 + 4];
        float vals[8] = {acc[i][0]+r0.x, acc[i][1]+r0.y, acc[i][2]+r0.z, acc[i][3]+r0.w,
                         acc[i][4]+r1.x, acc[i][5]+r1.y, acc[i][6]+r1.z, acc[i][7]+r1.w};
        float s = 0.f, s2 = 0.f;
        #pragma unroll
        for (int j = 0; j < 8; j++) { s += vals[j]; s2 += vals[j] * vals[j]; }
        #pragma unroll
        for (int off = 16; off; off >>= 1) {
            s  += __shfl_xor(s,  off);
            s2 += __shfl_xor(s2, off);
        }
        float mu  = s  * 0.00390625f;
        float var = s2 * 0.00390625f - mu * mu;
        float rs  = rsqrtf(var + 1e-6f);
        float o8[8];
        #pragma unroll
        for (int j = 0; j < 8; j++) o8[j] = (vals[j] - mu) * rs * gv[j] + bv8[j];
        *(float4*)&out[m * 256 + cq * 8]     = make_float4(o8[0], o8[1], o8[2], o8[3]);
        *(float4*)&out[m * 256 + cq * 8 + 4] = make_float4(o8[4], o8[5], o8[6], o8[7]);
    }
}

// ---------------------------------------------------------------------------
extern "C" void kernel_launch(void* const* d_in, const int* in_sizes, int n_in,
                              void* d_out, int out_size, void* d_ws, size_t ws_size,
                              hipStream_t stream)
{
    const float* q   = (const float*)d_in[0];
    const float* v   = (const float*)d_in[2];
    const float* wqs = (const float*)d_in[3];
    const float* wvs = (const float*)d_in[4];
    const float* w1  = (const float*)d_in[5];
    const float* b1  = (const float*)d_in[6];
    const float* w2  = (const float*)d_in[7];
    const float* b2  = (const float*)d_in[8];
    const float* fcw = (const float*)d_in[9];
    const float* lng = (const float*)d_in[10];
    const float* lnb = (const float*)d_in[11];
    float* out = (float*)d_out;

    u16* qh_bf = (u16*)d_ws;                       // 8,200,192 el (padded; OOB rows stay in-bounds)
    u16* vhT   = qh_bf + 8200192;                  // 256*64*512 = 8,388,608 el
    u16* w1T   = vhT + 8388608;                    // 4096 el
    u16* w2T   = w1T + 4096;                       // 32768 el
    float* ctx = (float*)(w2T + 32768);            // 8,192,000 el fp32

    prep_kernel <<<dim3(32),      256, 0, stream>>>(w1, w2, w1T, w2T);
    proj_kernel <<<dim3(500, 2),  256, 0, stream>>>(q, v, wqs, wvs, qh_bf, vhT);
    attn_kernel <<<dim3(8, 256),  256, 0, stream>>>(qh_bf, vhT, w1T, b1, w2T, b2, ctx);
    final_kernel<<<dim3(500),     256, 0, stream>>>(ctx, fcw, q, lng, lnb, out);
}

// Round 3
// 299.438 us; speedup vs baseline: 2.3654x; 1.3571x over previous
//
#include <hip/hip_runtime.h>
#include <math.h>

#define B_   64
#define L_   500
#define F_   256
#define H_   4
#define DK   64

typedef unsigned short u16;
typedef unsigned int   u32;
typedef __attribute__((ext_vector_type(8))) short short8;
typedef __attribute__((ext_vector_type(4))) float f32x4;

static __device__ __forceinline__ u16 f2bf(float f) {
    u32 u = __float_as_uint(f);
    u32 r = (u + 0x7FFFu + ((u >> 16) & 1u)) >> 16;
    return (u16)r;
}

// ---------------------------------------------------------------------------
// Prep: bf16 transposed weights.
//  wqT/wvT/fcwT [256][256] ([n][k]); w1T[64][64]; w2T[512][64] (n>=500 -> 0)
// ---------------------------------------------------------------------------
__global__ __launch_bounds__(256) void prep_kernel(
    const float* __restrict__ wq, const float* __restrict__ wv,
    const float* __restrict__ fcw, const float* __restrict__ w1,
    const float* __restrict__ w2,
    u16* __restrict__ wqT, u16* __restrict__ wvT, u16* __restrict__ fcwT,
    u16* __restrict__ w1T, u16* __restrict__ w2T)
{
    int t = blockIdx.x * 256 + threadIdx.x;
    int stride = gridDim.x * 256;
    for (int i = t; i < 256 * 256; i += stride) {
        int n = i >> 8, k = i & 255;
        wqT[i]  = f2bf(wq[k * 256 + n]);
        wvT[i]  = f2bf(wv[k * 256 + n]);
        fcwT[i] = f2bf(fcw[k * 256 + n]);
    }
    for (int i = t; i < 64 * 64; i += stride) {
        int n = i >> 6, k = i & 63;
        w1T[i] = f2bf(w1[k * 64 + n]);
    }
    for (int i = t; i < 512 * 64; i += stride) {
        int n = i >> 6, k = i & 63;
        w2T[i] = f2bf(n < 500 ? w2[k * 500 + n] : 0.f);
    }
}

// ---------------------------------------------------------------------------
// Kernel 1: head projections, bf16 MFMA.
// grid (250, 2), block 256 = 4 waves in 2x2; block tile 128 rows x 256 cols.
//  which=0: qh_bf [bh][500][64]; which=1: vhT [bh][64][512]
// ---------------------------------------------------------------------------
__global__ __launch_bounds__(256) void proj_kernel(
    const float* __restrict__ q, const float* __restrict__ v,
    const u16* __restrict__ wqT, const u16* __restrict__ wvT,
    u16* __restrict__ qh_bf, u16* __restrict__ vhT)
{
    const int which = blockIdx.y;
    const float* __restrict__ x = which ? v : q;
    const u16*   __restrict__ wT = which ? wvT : wqT;

    __shared__ u16 Xs[128][72];   // [m][k], pad 144 B
    __shared__ u16 Ws[256][72];   // [n][k], pad 144 B

    const int tid  = threadIdx.x;
    const int wvid = tid >> 6, ln = tid & 63;
    const int n16  = ln & 15, quad = ln >> 4;
    const int wr   = wvid >> 1, wc = wvid & 1;
    const int row0 = blockIdx.x * 128;

    f32x4 acc[4][8];
    #pragma unroll
    for (int mt = 0; mt < 4; mt++)
        #pragma unroll
        for (int nt = 0; nt < 8; nt++) acc[mt][nt] = (f32x4){0.f, 0.f, 0.f, 0.f};

    for (int kc = 0; kc < 256; kc += 64) {
        // stage X (fp32 -> bf16): 128 x 64
        #pragma unroll
        for (int j = 0; j < 8; j++) {
            int idx = tid + 256 * j;
            int m = idx >> 4, k4 = idx & 15;
            float4 a = *(const float4*)&x[(size_t)(row0 + m) * 256 + kc + k4 * 4];
            __align__(8) u16 t4[4] = {f2bf(a.x), f2bf(a.y), f2bf(a.z), f2bf(a.w)};
            *(uint2*)&Xs[m][k4 * 4] = *(const uint2*)t4;
        }
        // stage W^T: 256 x 64 bf16
        #pragma unroll
        for (int j = 0; j < 8; j++) {
            int idx = tid + 256 * j;
            int n = idx >> 3, k8 = idx & 7;
            *(uint4*)&Ws[n][k8 * 8] = *(const uint4*)&wT[n * 256 + kc + k8 * 8];
        }
        __syncthreads();
        #pragma unroll
        for (int ks = 0; ks < 2; ks++) {
            short8 af[4], bfr[8];
            #pragma unroll
            for (int mt = 0; mt < 4; mt++)
                af[mt] = *(const short8*)&Xs[wr * 64 + mt * 16 + n16][ks * 32 + quad * 8];
            #pragma unroll
            for (int nt = 0; nt < 8; nt++)
                bfr[nt] = *(const short8*)&Ws[wc * 128 + nt * 16 + n16][ks * 32 + quad * 8];
            #pragma unroll
            for (int mt = 0; mt < 4; mt++)
                #pragma unroll
                for (int nt = 0; nt < 8; nt++)
                    acc[mt][nt] = __builtin_amdgcn_mfma_f32_16x16x32_bf16(
                        af[mt], bfr[nt], acc[mt][nt], 0, 0, 0);
        }
        __syncthreads();
    }

    if (which == 0) {
        // qh[bh][l][d]
        #pragma unroll
        for (int mt = 0; mt < 4; mt++) {
            int m0 = row0 + wr * 64 + mt * 16 + quad * 4;   // mult of 4
            int b  = m0 / 500;
            int l0 = m0 - 500 * b;
            #pragma unroll
            for (int nt = 0; nt < 8; nt++) {
                int col = wc * 128 + nt * 16 + n16;
                int h = col >> 6, d = col & 63;
                u16* dst = qh_bf + ((size_t)((b * 4 + h) * 500 + l0)) * 64 + d;
                #pragma unroll
                for (int i = 0; i < 4; i++)
                    dst[(size_t)i * 64] = f2bf(acc[mt][nt][i]);
            }
        }
    } else {
        // vhT[bh][d][l], 4 consecutive l per lane -> uint2
        #pragma unroll
        for (int mt = 0; mt < 4; mt++) {
            int m0 = row0 + wr * 64 + mt * 16 + quad * 4;   // mult of 4, same b
            int b  = m0 / 500;
            int l0 = m0 - 500 * b;
            #pragma unroll
            for (int nt = 0; nt < 8; nt++) {
                int col = wc * 128 + nt * 16 + n16;
                int h = col >> 6, d = col & 63;
                __align__(8) u16 t4[4];
                #pragma unroll
                for (int i = 0; i < 4; i++) t4[i] = f2bf(acc[mt][nt][i]);
                *(uint2*)&vhT[((size_t)((b * 4 + h) * 64 + d)) * 512 + l0] =
                    *(const uint2*)t4;
            }
        }
    }
}

// ---------------------------------------------------------------------------
// Kernel 2: dense-synthesizer attention, bf16 MFMA (ctx output now bf16).
// grid (8, 256), block 256.
// ---------------------------------------------------------------------------
__global__ __launch_bounds__(256) void attn_kernel(
    const u16* __restrict__ qh, const u16* __restrict__ vhT,
    const u16* __restrict__ w1T, const float* __restrict__ b1,
    const u16* __restrict__ w2T, const float* __restrict__ b2,
    u16* __restrict__ ctx)
{
    __shared__ u16 s_lds[4][16][72];
    __shared__ u16 p_lds[4][16][136];
    __shared__ u16 v_lds[64][136];

    const int tid  = threadIdx.x;
    const int wv   = tid >> 6;
    const int ln   = tid & 63;
    const int n16  = ln & 15;
    const int quad = ln >> 4;
    const int bh   = blockIdx.y;
    const int r0   = blockIdx.x * 64 + wv * 16;

    // ---- Phase A: s = relu(qh @ w1 + b1) ----
    {
        const u16* qbase = qh + ((size_t)(bh * 500 + r0 + n16)) * 64;
        short8 a0 = *(const short8*)(qbase + quad * 8);
        short8 a1 = *(const short8*)(qbase + 32 + quad * 8);
        #pragma unroll
        for (int nt = 0; nt < 4; nt++) {
            const u16* wb = w1T + (nt * 16 + n16) * 64;
            short8 bb0 = *(const short8*)(wb + quad * 8);
            short8 bb1 = *(const short8*)(wb + 32 + quad * 8);
            f32x4 c = {0.f, 0.f, 0.f, 0.f};
            c = __builtin_amdgcn_mfma_f32_16x16x32_bf16(a0, bb0, c, 0, 0, 0);
            c = __builtin_amdgcn_mfma_f32_16x16x32_bf16(a1, bb1, c, 0, 0, 0);
            float bias = b1[nt * 16 + n16];
            #pragma unroll
            for (int i = 0; i < 4; i++)
                s_lds[wv][quad * 4 + i][nt * 16 + n16] = f2bf(fmaxf(c[i] + bias, 0.f));
        }
    }
    __syncthreads();

    // ---- Phase B: logits ----
    f32x4 acc[32];
    {
        short8 sa0 = *(const short8*)&s_lds[wv][n16][quad * 8];
        short8 sa1 = *(const short8*)&s_lds[wv][n16][32 + quad * 8];
        #pragma unroll
        for (int nt = 0; nt < 32; nt++) {
            const u16* wb = w2T + (nt * 16 + n16) * 64;
            short8 bb0 = *(const short8*)(wb + quad * 8);
            short8 bb1 = *(const short8*)(wb + 32 + quad * 8);
            f32x4 c = {0.f, 0.f, 0.f, 0.f};
            c = __builtin_amdgcn_mfma_f32_16x16x32_bf16(sa0, bb0, c, 0, 0, 0);
            c = __builtin_amdgcn_mfma_f32_16x16x32_bf16(sa1, bb1, c, 0, 0, 0);
            int col = nt * 16 + n16;
            float bias = (col < 500) ? b2[col] : -INFINITY;
            #pragma unroll
            for (int i = 0; i < 4; i++) c[i] += bias;
            acc[nt] = c;
        }
    }

    // ---- softmax stats (P unnormalized; fold 1/sum into epilogue) ----
    float inv[4];
    {
        float mx[4], sm[4];
        #pragma unroll
        for (int i = 0; i < 4; i++) mx[i] = acc[0][i];
        #pragma unroll
        for (int nt = 1; nt < 32; nt++)
            #pragma unroll
            for (int i = 0; i < 4; i++) mx[i] = fmaxf(mx[i], acc[nt][i]);
        #pragma unroll
        for (int off = 1; off < 16; off <<= 1)
            #pragma unroll
            for (int i = 0; i < 4; i++) mx[i] = fmaxf(mx[i], __shfl_xor(mx[i], off));
        #pragma unroll
        for (int i = 0; i < 4; i++) sm[i] = 0.f;
        #pragma unroll
        for (int nt = 0; nt < 32; nt++)
            #pragma unroll
            for (int i = 0; i < 4; i++) {
                float e = __expf(acc[nt][i] - mx[i]);
                acc[nt][i] = e;
                sm[i] += e;
            }
        #pragma unroll
        for (int off = 1; off < 16; off <<= 1)
            #pragma unroll
            for (int i = 0; i < 4; i++) sm[i] += __shfl_xor(sm[i], off);
        #pragma unroll
        for (int i = 0; i < 4; i++) inv[i] = 1.f / sm[i];
    }

    // ---- Phase C: out = P @ vh in 4 K-chunks of 128 ----
    f32x4 oacc[4];
    #pragma unroll
    for (int nt = 0; nt < 4; nt++) oacc[nt] = (f32x4){0.f, 0.f, 0.f, 0.f};

    for (int cc = 0; cc < 4; cc++) {
        #pragma unroll
        for (int u = tid; u < 1024; u += 256) {
            int d  = u >> 4;
            int kk = (u & 15) * 8;
            *(short8*)&v_lds[d][kk] =
                *(const short8*)(vhT + ((size_t)(bh * 64 + d)) * 512 + cc * 128 + kk);
        }
        #pragma unroll
        for (int t = 0; t < 8; t++) {
            int nt = cc * 8 + t;
            int c  = t * 16 + n16;
            #pragma unroll
            for (int i = 0; i < 4; i++)
                p_lds[wv][quad * 4 + i][c] = f2bf(acc[nt][i]);
        }
        __syncthreads();
        #pragma unroll
        for (int ks = 0; ks < 4; ks++) {
            short8 pa = *(const short8*)&p_lds[wv][n16][ks * 32 + quad * 8];
            #pragma unroll
            for (int nt = 0; nt < 4; nt++) {
                short8 vb = *(const short8*)&v_lds[nt * 16 + n16][ks * 32 + quad * 8];
                oacc[nt] = __builtin_amdgcn_mfma_f32_16x16x32_bf16(pa, vb, oacc[nt], 0, 0, 0);
            }
        }
        __syncthreads();
    }

    // ---- epilogue: scale, write ctx bf16 ----
    {
        const int b = bh >> 2, h = bh & 3;
        #pragma unroll
        for (int i = 0; i < 4; i++) {
            int lrow = r0 + quad * 4 + i;
            if (lrow < 500) {
                float s = inv[i];
                u16* dst = &ctx[((size_t)(b * 500 + lrow)) * 256 + h * 64];
                #pragma unroll
                for (int nt = 0; nt < 4; nt++)
                    dst[nt * 16 + n16] = f2bf(oacc[nt][i] * s);
            }
        }
    }
}

// ---------------------------------------------------------------------------
// Kernel 3: out = LayerNorm(ctx @ fc_w + q), bf16 MFMA + fused LN epilogue.
// grid (250), block 256 = 4 waves 2x2; tile 128 x 256.
// ---------------------------------------------------------------------------
__global__ __launch_bounds__(256) void final_kernel(
    const u16* __restrict__ ctx, const u16* __restrict__ fcwT,
    const float* __restrict__ qres, const float* __restrict__ g,
    const float* __restrict__ bta, float* __restrict__ out)
{
    __shared__ u16 Xs[128][72];
    __shared__ u16 Ws[256][72];
    __shared__ float red[2][2][128];   // [wc][s1|s2][row]
    __shared__ float murs[2][128];     // [mu|rs][row]

    const int tid  = threadIdx.x;
    const int wvid = tid >> 6, ln = tid & 63;
    const int n16  = ln & 15, quad = ln >> 4;
    const int wr   = wvid >> 1, wc = wvid & 1;
    const int row0 = blockIdx.x * 128;

    f32x4 acc[4][8];
    #pragma unroll
    for (int mt = 0; mt < 4; mt++)
        #pragma unroll
        for (int nt = 0; nt < 8; nt++) acc[mt][nt] = (f32x4){0.f, 0.f, 0.f, 0.f};

    for (int kc = 0; kc < 256; kc += 64) {
        #pragma unroll
        for (int j = 0; j < 4; j++) {
            int idx = tid + 256 * j;
            int m = idx >> 3, k8 = idx & 7;
            *(uint4*)&Xs[m][k8 * 8] =
                *(const uint4*)&ctx[(size_t)(row0 + m) * 256 + kc + k8 * 8];
        }
        #pragma unroll
        for (int j = 0; j < 8; j++) {
            int idx = tid + 256 * j;
            int n = idx >> 3, k8 = idx & 7;
            *(uint4*)&Ws[n][k8 * 8] = *(const uint4*)&fcwT[n * 256 + kc + k8 * 8];
        }
        __syncthreads();
        #pragma unroll
        for (int ks = 0; ks < 2; ks++) {
            short8 af[4], bfr[8];
            #pragma unroll
            for (int mt = 0; mt < 4; mt++)
                af[mt] = *(const short8*)&Xs[wr * 64 + mt * 16 + n16][ks * 32 + quad * 8];
            #pragma unroll
            for (int nt = 0; nt < 8; nt++)
                bfr[nt] = *(const short8*)&Ws[wc * 128 + nt * 16 + n16][ks * 32 + quad * 8];
            #pragma unroll
            for (int mt = 0; mt < 4; mt++)
                #pragma unroll
                for (int nt = 0; nt < 8; nt++)
                    acc[mt][nt] = __builtin_amdgcn_mfma_f32_16x16x32_bf16(
                        af[mt], bfr[nt], acc[mt][nt], 0, 0, 0);
        }
        __syncthreads();
    }

    // residual add
    #pragma unroll
    for (int mt = 0; mt < 4; mt++) {
        int m0 = row0 + wr * 64 + mt * 16 + quad * 4;
        #pragma unroll
        for (int i = 0; i < 4; i++) {
            const float* rp = &qres[(size_t)(m0 + i) * 256 + wc * 128 + n16];
            #pragma unroll
            for (int nt = 0; nt < 8; nt++)
                acc[mt][nt][i] += rp[nt * 16];
        }
    }
    // per-row partial sums -> LDS
    #pragma unroll
    for (int mt = 0; mt < 4; mt++) {
        #pragma unroll
        for (int i = 0; i < 4; i++) {
            float s1 = 0.f, s2 = 0.f;
            #pragma unroll
            for (int nt = 0; nt < 8; nt++) {
                float vv = acc[mt][nt][i];
                s1 += vv; s2 += vv * vv;
            }
            #pragma unroll
            for (int off = 1; off < 16; off <<= 1) {
                s1 += __shfl_xor(s1, off);
                s2 += __shfl_xor(s2, off);
            }
            if (n16 == 0) {
                int r = wr * 64 + mt * 16 + quad * 4 + i;
                red[wc][0][r] = s1;
                red[wc][1][r] = s2;
            }
        }
    }
    __syncthreads();
    if (tid < 128) {
        float S1 = red[0][0][tid] + red[1][0][tid];
        float S2 = red[0][1][tid] + red[1][1][tid];
        float mu  = S1 * 0.00390625f;
        float var = S2 * 0.00390625f - mu * mu;
        murs[0][tid] = mu;
        murs[1][tid] = rsqrtf(var + 1e-6f);
    }
    __syncthreads();

    float gv[8], bv[8];
    #pragma unroll
    for (int nt = 0; nt < 8; nt++) {
        int col = wc * 128 + nt * 16 + n16;
        gv[nt] = g[col];
        bv[nt] = bta[col];
    }
    #pragma unroll
    for (int mt = 0; mt < 4; mt++) {
        int rb = wr * 64 + mt * 16 + quad * 4;
        #pragma unroll
        for (int i = 0; i < 4; i++) {
            float mu = murs[0][rb + i];
            float rs = murs[1][rb + i];
            float* op = &out[(size_t)(row0 + rb + i) * 256 + wc * 128 + n16];
            #pragma unroll
            for (int nt = 0; nt < 8; nt++)
                op[nt * 16] = (acc[mt][nt][i] - mu) * rs * gv[nt] + bv[nt];
        }
    }
}

// ---------------------------------------------------------------------------
extern "C" void kernel_launch(void* const* d_in, const int* in_sizes, int n_in,
                              void* d_out, int out_size, void* d_ws, size_t ws_size,
                              hipStream_t stream)
{
    const float* q   = (const float*)d_in[0];
    const float* v   = (const float*)d_in[2];
    const float* wqs = (const float*)d_in[3];
    const float* wvs = (const float*)d_in[4];
    const float* w1  = (const float*)d_in[5];
    const float* b1  = (const float*)d_in[6];
    const float* w2  = (const float*)d_in[7];
    const float* b2  = (const float*)d_in[8];
    const float* fcw = (const float*)d_in[9];
    const float* lng = (const float*)d_in[10];
    const float* lnb = (const float*)d_in[11];
    float* out = (float*)d_out;

    u16* qh_bf = (u16*)d_ws;            // 8,200,192 (padded: attn reads rows <512)
    u16* vhT   = qh_bf + 8200192;       // 8,388,608
    u16* w1T   = vhT + 8388608;         // 4,096
    u16* w2T   = w1T + 4096;            // 32,768
    u16* wqT   = w2T + 32768;           // 65,536
    u16* wvT   = wqT + 65536;           // 65,536
    u16* fcwT  = wvT + 65536;           // 65,536
    u16* ctx   = fcwT + 65536;          // 8,192,000

    prep_kernel <<<dim3(64),     256, 0, stream>>>(wqs, wvs, fcw, w1, w2,
                                                   wqT, wvT, fcwT, w1T, w2T);
    proj_kernel <<<dim3(250, 2), 256, 0, stream>>>(q, v, wqT, wvT, qh_bf, vhT);
    attn_kernel <<<dim3(8, 256), 256, 0, stream>>>(qh_bf, vhT, w1T, b1, w2T, b2, ctx);
    final_kernel<<<dim3(250),    256, 0, stream>>>(ctx, fcwT, q, lng, lnb, out);
}

// Round 4
// 265.294 us; speedup vs baseline: 2.6698x; 1.1287x over previous
//
#include <hip/hip_runtime.h>
#include <math.h>

#define B_   64
#define L_   500
#define F_   256
#define H_   4
#define DK   64

typedef unsigned short u16;
typedef unsigned int   u32;
typedef __attribute__((ext_vector_type(8))) short short8;
typedef __attribute__((ext_vector_type(4))) float f32x4;

static __device__ __forceinline__ u16 f2bf(float f) {
    u32 u = __float_as_uint(f);
    u32 r = (u + 0x7FFFu + ((u >> 16) & 1u)) >> 16;
    return (u16)r;
}

// ---------------------------------------------------------------------------
// Prep: bf16 transposed weights.
//  wqT/wvT/fcwT [256][256] ([n][k]); w1T[64][64]; w2T[512][64] (n>=500 -> 0)
// ---------------------------------------------------------------------------
__global__ __launch_bounds__(256) void prep_kernel(
    const float* __restrict__ wq, const float* __restrict__ wv,
    const float* __restrict__ fcw, const float* __restrict__ w1,
    const float* __restrict__ w2,
    u16* __restrict__ wqT, u16* __restrict__ wvT, u16* __restrict__ fcwT,
    u16* __restrict__ w1T, u16* __restrict__ w2T)
{
    int t = blockIdx.x * 256 + threadIdx.x;
    int stride = gridDim.x * 256;
    for (int i = t; i < 256 * 256; i += stride) {
        int n = i >> 8, k = i & 255;
        wqT[i]  = f2bf(wq[k * 256 + n]);
        wvT[i]  = f2bf(wv[k * 256 + n]);
        fcwT[i] = f2bf(fcw[k * 256 + n]);
    }
    for (int i = t; i < 64 * 64; i += stride) {
        int n = i >> 6, k = i & 63;
        w1T[i] = f2bf(w1[k * 64 + n]);
    }
    for (int i = t; i < 512 * 64; i += stride) {
        int n = i >> 6, k = i & 63;
        w2T[i] = f2bf(n < 500 ? w2[k * 500 + n] : 0.f);
    }
}

// ---------------------------------------------------------------------------
// Kernel 1: head projections, bf16 MFMA.
// grid (250, 2), block 256 = 4 waves in 2x2; block tile 128 rows x 256 cols.
//  which=0: qh_bf [bh][500][64]; which=1: vhT [bh][64][512]
// ---------------------------------------------------------------------------
__global__ __launch_bounds__(256) void proj_kernel(
    const float* __restrict__ q, const float* __restrict__ v,
    const u16* __restrict__ wqT, const u16* __restrict__ wvT,
    u16* __restrict__ qh_bf, u16* __restrict__ vhT)
{
    const int which = blockIdx.y;
    const float* __restrict__ x = which ? v : q;
    const u16*   __restrict__ wT = which ? wvT : wqT;

    __shared__ u16 Xs[128][72];   // [m][k], pad 144 B
    __shared__ u16 Ws[256][72];   // [n][k], pad 144 B

    const int tid  = threadIdx.x;
    const int wvid = tid >> 6, ln = tid & 63;
    const int n16  = ln & 15, quad = ln >> 4;
    const int wr   = wvid >> 1, wc = wvid & 1;
    const int row0 = blockIdx.x * 128;

    f32x4 acc[4][8];
    #pragma unroll
    for (int mt = 0; mt < 4; mt++)
        #pragma unroll
        for (int nt = 0; nt < 8; nt++) acc[mt][nt] = (f32x4){0.f, 0.f, 0.f, 0.f};

    for (int kc = 0; kc < 256; kc += 64) {
        // stage X (fp32 -> bf16): 128 x 64
        #pragma unroll
        for (int j = 0; j < 8; j++) {
            int idx = tid + 256 * j;
            int m = idx >> 4, k4 = idx & 15;
            float4 a = *(const float4*)&x[(size_t)(row0 + m) * 256 + kc + k4 * 4];
            __align__(8) u16 t4[4] = {f2bf(a.x), f2bf(a.y), f2bf(a.z), f2bf(a.w)};
            *(uint2*)&Xs[m][k4 * 4] = *(const uint2*)t4;
        }
        // stage W^T: 256 x 64 bf16
        #pragma unroll
        for (int j = 0; j < 8; j++) {
            int idx = tid + 256 * j;
            int n = idx >> 3, k8 = idx & 7;
            *(uint4*)&Ws[n][k8 * 8] = *(const uint4*)&wT[n * 256 + kc + k8 * 8];
        }
        __syncthreads();
        #pragma unroll
        for (int ks = 0; ks < 2; ks++) {
            short8 af[4], bfr[8];
            #pragma unroll
            for (int mt = 0; mt < 4; mt++)
                af[mt] = *(const short8*)&Xs[wr * 64 + mt * 16 + n16][ks * 32 + quad * 8];
            #pragma unroll
            for (int nt = 0; nt < 8; nt++)
                bfr[nt] = *(const short8*)&Ws[wc * 128 + nt * 16 + n16][ks * 32 + quad * 8];
            #pragma unroll
            for (int mt = 0; mt < 4; mt++)
                #pragma unroll
                for (int nt = 0; nt < 8; nt++)
                    acc[mt][nt] = __builtin_amdgcn_mfma_f32_16x16x32_bf16(
                        af[mt], bfr[nt], acc[mt][nt], 0, 0, 0);
        }
        __syncthreads();
    }

    if (which == 0) {
        // qh[bh][l][d]
        #pragma unroll
        for (int mt = 0; mt < 4; mt++) {
            int m0 = row0 + wr * 64 + mt * 16 + quad * 4;   // mult of 4
            int b  = m0 / 500;
            int l0 = m0 - 500 * b;
            #pragma unroll
            for (int nt = 0; nt < 8; nt++) {
                int col = wc * 128 + nt * 16 + n16;
                int h = col >> 6, d = col & 63;
                u16* dst = qh_bf + ((size_t)((b * 4 + h) * 500 + l0)) * 64 + d;
                #pragma unroll
                for (int i = 0; i < 4; i++)
                    dst[(size_t)i * 64] = f2bf(acc[mt][nt][i]);
            }
        }
    } else {
        // vhT[bh][d][l], 4 consecutive l per lane -> uint2
        #pragma unroll
        for (int mt = 0; mt < 4; mt++) {
            int m0 = row0 + wr * 64 + mt * 16 + quad * 4;   // mult of 4, same b
            int b  = m0 / 500;
            int l0 = m0 - 500 * b;
            #pragma unroll
            for (int nt = 0; nt < 8; nt++) {
                int col = wc * 128 + nt * 16 + n16;
                int h = col >> 6, d = col & 63;
                __align__(8) u16 t4[4];
                #pragma unroll
                for (int i = 0; i < 4; i++) t4[i] = f2bf(acc[mt][nt][i]);
                *(uint2*)&vhT[((size_t)((b * 4 + h) * 64 + d)) * 512 + l0] =
                    *(const uint2*)t4;
            }
        }
    }
}

// ---------------------------------------------------------------------------
// Kernel 2: dense-synthesizer attention, bf16 MFMA.
// grid (256 bh, 8 row-chunks) so same-bh blocks land on the same XCD.
// LDS: one 36 KB union region (s_tmp | w2 double-buffer | v+p) -> 4 blk/CU.
// ---------------------------------------------------------------------------
__global__ __launch_bounds__(256) void attn_kernel(
    const u16* __restrict__ qh, const u16* __restrict__ vhT,
    const u16* __restrict__ w1T, const float* __restrict__ b1,
    const u16* __restrict__ w2T, const float* __restrict__ b2,
    u16* __restrict__ ctx)
{
    __shared__ __align__(16) char lds_raw[36864];
    u16 (*s_tmp)[16][72]  = (u16 (*)[16][72])  lds_raw;             // [4][16][72]
    u16 (*w2s)[128][72]   = (u16 (*)[128][72]) lds_raw;             // [2][128][72]
    u16 (*v_lds)[136]     = (u16 (*)[136])     lds_raw;             // [64][136]
    u16 (*p_lds)[16][136] = (u16 (*)[16][136]) (lds_raw + 17408);   // [4][16][136]

    const int tid  = threadIdx.x;
    const int wv   = tid >> 6;
    const int ln   = tid & 63;
    const int n16  = ln & 15;
    const int quad = ln >> 4;
    const int bh   = blockIdx.x;
    const int r0   = blockIdx.y * 64 + wv * 16;

    // ---- Phase A: s = relu(qh @ w1 + b1), C-layout -> LDS -> A-frag regs ----
    {
        const u16* qbase = qh + ((size_t)(bh * 500 + r0 + n16)) * 64;
        short8 a0 = *(const short8*)(qbase + quad * 8);
        short8 a1 = *(const short8*)(qbase + 32 + quad * 8);
        #pragma unroll
        for (int nt = 0; nt < 4; nt++) {
            const u16* wb = w1T + (nt * 16 + n16) * 64;
            short8 bb0 = *(const short8*)(wb + quad * 8);
            short8 bb1 = *(const short8*)(wb + 32 + quad * 8);
            f32x4 c = {0.f, 0.f, 0.f, 0.f};
            c = __builtin_amdgcn_mfma_f32_16x16x32_bf16(a0, bb0, c, 0, 0, 0);
            c = __builtin_amdgcn_mfma_f32_16x16x32_bf16(a1, bb1, c, 0, 0, 0);
            float bias = b1[nt * 16 + n16];
            #pragma unroll
            for (int i = 0; i < 4; i++)
                s_tmp[wv][quad * 4 + i][nt * 16 + n16] = f2bf(fmaxf(c[i] + bias, 0.f));
        }
    }
    __syncthreads();
    short8 sa0 = *(const short8*)&s_tmp[wv][n16][quad * 8];
    short8 sa1 = *(const short8*)&s_tmp[wv][n16][32 + quad * 8];
    __syncthreads();   // s_tmp region about to be reused for w2 staging

    // ---- Phase B: logits = s @ w2 + b2; w2T staged in LDS, double-buffered ----
    f32x4 acc[32];
    {
        // stage chunk 0
        #pragma unroll
        for (int j = 0; j < 4; j++) {
            int idx = tid + 256 * j;
            int n = idx >> 3, k8 = idx & 7;
            *(uint4*)&w2s[0][n][k8 * 8] = *(const uint4*)&w2T[n * 64 + k8 * 8];
        }
        __syncthreads();
        for (int cc = 0; cc < 4; cc++) {
            if (cc < 3) {
                const u16* src = w2T + (cc + 1) * 128 * 64;
                #pragma unroll
                for (int j = 0; j < 4; j++) {
                    int idx = tid + 256 * j;
                    int n = idx >> 3, k8 = idx & 7;
                    *(uint4*)&w2s[(cc + 1) & 1][n][k8 * 8] =
                        *(const uint4*)&src[n * 64 + k8 * 8];
                }
            }
            u16 (*buf)[72] = w2s[cc & 1];
            #pragma unroll
            for (int t = 0; t < 8; t++) {
                int nt = cc * 8 + t;
                short8 bb0 = *(const short8*)&buf[t * 16 + n16][quad * 8];
                short8 bb1 = *(const short8*)&buf[t * 16 + n16][32 + quad * 8];
                f32x4 c = {0.f, 0.f, 0.f, 0.f};
                c = __builtin_amdgcn_mfma_f32_16x16x32_bf16(sa0, bb0, c, 0, 0, 0);
                c = __builtin_amdgcn_mfma_f32_16x16x32_bf16(sa1, bb1, c, 0, 0, 0);
                int col = nt * 16 + n16;
                float bias = (col < 500) ? b2[col] : -INFINITY;
                #pragma unroll
                for (int i = 0; i < 4; i++) c[i] += bias;
                acc[nt] = c;
            }
            __syncthreads();
        }
    }

    // ---- softmax stats (P unnormalized; fold 1/sum into epilogue) ----
    float inv[4];
    {
        float mx[4], sm[4];
        #pragma unroll
        for (int i = 0; i < 4; i++) mx[i] = acc[0][i];
        #pragma unroll
        for (int nt = 1; nt < 32; nt++)
            #pragma unroll
            for (int i = 0; i < 4; i++) mx[i] = fmaxf(mx[i], acc[nt][i]);
        #pragma unroll
        for (int off = 1; off < 16; off <<= 1)
            #pragma unroll
            for (int i = 0; i < 4; i++) mx[i] = fmaxf(mx[i], __shfl_xor(mx[i], off));
        #pragma unroll
        for (int i = 0; i < 4; i++) sm[i] = 0.f;
        #pragma unroll
        for (int nt = 0; nt < 32; nt++)
            #pragma unroll
            for (int i = 0; i < 4; i++) {
                float e = __expf(acc[nt][i] - mx[i]);
                acc[nt][i] = e;
                sm[i] += e;
            }
        #pragma unroll
        for (int off = 1; off < 16; off <<= 1)
            #pragma unroll
            for (int i = 0; i < 4; i++) sm[i] += __shfl_xor(sm[i], off);
        #pragma unroll
        for (int i = 0; i < 4; i++) inv[i] = 1.f / sm[i];
    }

    // ---- Phase C: out = P @ vh in 4 K-chunks of 128 ----
    f32x4 oacc[4];
    #pragma unroll
    for (int nt = 0; nt < 4; nt++) oacc[nt] = (f32x4){0.f, 0.f, 0.f, 0.f};

    for (int cc = 0; cc < 4; cc++) {
        #pragma unroll
        for (int u = tid; u < 1024; u += 256) {
            int d  = u >> 4;
            int kk = (u & 15) * 8;
            *(short8*)&v_lds[d][kk] =
                *(const short8*)(vhT + ((size_t)(bh * 64 + d)) * 512 + cc * 128 + kk);
        }
        #pragma unroll
        for (int t = 0; t < 8; t++) {
            int nt = cc * 8 + t;
            int c  = t * 16 + n16;
            #pragma unroll
            for (int i = 0; i < 4; i++)
                p_lds[wv][quad * 4 + i][c] = f2bf(acc[nt][i]);
        }
        __syncthreads();
        #pragma unroll
        for (int ks = 0; ks < 4; ks++) {
            short8 pa = *(const short8*)&p_lds[wv][n16][ks * 32 + quad * 8];
            #pragma unroll
            for (int nt = 0; nt < 4; nt++) {
                short8 vb = *(const short8*)&v_lds[nt * 16 + n16][ks * 32 + quad * 8];
                oacc[nt] = __builtin_amdgcn_mfma_f32_16x16x32_bf16(pa, vb, oacc[nt], 0, 0, 0);
            }
        }
        __syncthreads();
    }

    // ---- epilogue: scale, write ctx bf16 ----
    {
        const int b = bh >> 2, h = bh & 3;
        #pragma unroll
        for (int i = 0; i < 4; i++) {
            int lrow = r0 + quad * 4 + i;
            if (lrow < 500) {
                float s = inv[i];
                u16* dst = &ctx[((size_t)(b * 500 + lrow)) * 256 + h * 64];
                #pragma unroll
                for (int nt = 0; nt < 4; nt++)
                    dst[nt * 16 + n16] = f2bf(oacc[nt][i] * s);
            }
        }
    }
}

// ---------------------------------------------------------------------------
// Kernel 3: out = LayerNorm(ctx @ fc_w + q), bf16 MFMA + fused LN epilogue.
// grid (250), block 256 = 4 waves 2x2; tile 128 x 256.
// ---------------------------------------------------------------------------
__global__ __launch_bounds__(256) void final_kernel(
    const u16* __restrict__ ctx, const u16* __restrict__ fcwT,
    const float* __restrict__ qres, const float* __restrict__ g,
    const float* __restrict__ bta, float* __restrict__ out)
{
    __shared__ u16 Xs[128][72];
    __shared__ u16 Ws[256][72];
    __shared__ float red[2][2][128];   // [wc][s1|s2][row]
    __shared__ float murs[2][128];     // [mu|rs][row]

    const int tid  = threadIdx.x;
    const int wvid = tid >> 6, ln = tid & 63;
    const int n16  = ln & 15, quad = ln >> 4;
    const int wr   = wvid >> 1, wc = wvid & 1;
    const int row0 = blockIdx.x * 128;

    f32x4 acc[4][8];
    #pragma unroll
    for (int mt = 0; mt < 4; mt++)
        #pragma unroll
        for (int nt = 0; nt < 8; nt++) acc[mt][nt] = (f32x4){0.f, 0.f, 0.f, 0.f};

    for (int kc = 0; kc < 256; kc += 64) {
        #pragma unroll
        for (int j = 0; j < 4; j++) {
            int idx = tid + 256 * j;
            int m = idx >> 3, k8 = idx & 7;
            *(uint4*)&Xs[m][k8 * 8] =
                *(const uint4*)&ctx[(size_t)(row0 + m) * 256 + kc + k8 * 8];
        }
        #pragma unroll
        for (int j = 0; j < 8; j++) {
            int idx = tid + 256 * j;
            int n = idx >> 3, k8 = idx & 7;
            *(uint4*)&Ws[n][k8 * 8] = *(const uint4*)&fcwT[n * 256 + kc + k8 * 8];
        }
        __syncthreads();
        #pragma unroll
        for (int ks = 0; ks < 2; ks++) {
            short8 af[4], bfr[8];
            #pragma unroll
            for (int mt = 0; mt < 4; mt++)
                af[mt] = *(const short8*)&Xs[wr * 64 + mt * 16 + n16][ks * 32 + quad * 8];
            #pragma unroll
            for (int nt = 0; nt < 8; nt++)
                bfr[nt] = *(const short8*)&Ws[wc * 128 + nt * 16 + n16][ks * 32 + quad * 8];
            #pragma unroll
            for (int mt = 0; mt < 4; mt++)
                #pragma unroll
                for (int nt = 0; nt < 8; nt++)
                    acc[mt][nt] = __builtin_amdgcn_mfma_f32_16x16x32_bf16(
                        af[mt], bfr[nt], acc[mt][nt], 0, 0, 0);
        }
        __syncthreads();
    }

    // residual add
    #pragma unroll
    for (int mt = 0; mt < 4; mt++) {
        int m0 = row0 + wr * 64 + mt * 16 + quad * 4;
        #pragma unroll
        for (int i = 0; i < 4; i++) {
            const float* rp = &qres[(size_t)(m0 + i) * 256 + wc * 128 + n16];
            #pragma unroll
            for (int nt = 0; nt < 8; nt++)
                acc[mt][nt][i] += rp[nt * 16];
        }
    }
    // per-row partial sums -> LDS
    #pragma unroll
    for (int mt = 0; mt < 4; mt++) {
        #pragma unroll
        for (int i = 0; i < 4; i++) {
            float s1 = 0.f, s2 = 0.f;
            #pragma unroll
            for (int nt = 0; nt < 8; nt++) {
                float vv = acc[mt][nt][i];
                s1 += vv; s2 += vv * vv;
            }
            #pragma unroll
            for (int off = 1; off < 16; off <<= 1) {
                s1 += __shfl_xor(s1, off);
                s2 += __shfl_xor(s2, off);
            }
            if (n16 == 0) {
                int r = wr * 64 + mt * 16 + quad * 4 + i;
                red[wc][0][r] = s1;
                red[wc][1][r] = s2;
            }
        }
    }
    __syncthreads();
    if (tid < 128) {
        float S1 = red[0][0][tid] + red[1][0][tid];
        float S2 = red[0][1][tid] + red[1][1][tid];
        float mu  = S1 * 0.00390625f;
        float var = S2 * 0.00390625f - mu * mu;
        murs[0][tid] = mu;
        murs[1][tid] = rsqrtf(var + 1e-6f);
    }
    __syncthreads();

    float gv[8], bv[8];
    #pragma unroll
    for (int nt = 0; nt < 8; nt++) {
        int col = wc * 128 + nt * 16 + n16;
        gv[nt] = g[col];
        bv[nt] = bta[col];
    }
    #pragma unroll
    for (int mt = 0; mt < 4; mt++) {
        int rb = wr * 64 + mt * 16 + quad * 4;
        #pragma unroll
        for (int i = 0; i < 4; i++) {
            float mu = murs[0][rb + i];
            float rs = murs[1][rb + i];
            float* op = &out[(size_t)(row0 + rb + i) * 256 + wc * 128 + n16];
            #pragma unroll
            for (int nt = 0; nt < 8; nt++)
                op[nt * 16] = (acc[mt][nt][i] - mu) * rs * gv[nt] + bv[nt];
        }
    }
}

// ---------------------------------------------------------------------------
extern "C" void kernel_launch(void* const* d_in, const int* in_sizes, int n_in,
                              void* d_out, int out_size, void* d_ws, size_t ws_size,
                              hipStream_t stream)
{
    const float* q   = (const float*)d_in[0];
    const float* v   = (const float*)d_in[2];
    const float* wqs = (const float*)d_in[3];
    const float* wvs = (const float*)d_in[4];
    const float* w1  = (const float*)d_in[5];
    const float* b1  = (const float*)d_in[6];
    const float* w2  = (const float*)d_in[7];
    const float* b2  = (const float*)d_in[8];
    const float* fcw = (const float*)d_in[9];
    const float* lng = (const float*)d_in[10];
    const float* lnb = (const float*)d_in[11];
    float* out = (float*)d_out;

    u16* qh_bf = (u16*)d_ws;            // 8,200,192 (padded: attn reads rows <512)
    u16* vhT   = qh_bf + 8200192;       // 8,388,608
    u16* w1T   = vhT + 8388608;         // 4,096
    u16* w2T   = w1T + 4096;            // 32,768
    u16* wqT   = w2T + 32768;           // 65,536
    u16* wvT   = wqT + 65536;           // 65,536
    u16* fcwT  = wvT + 65536;           // 65,536
    u16* ctx   = fcwT + 65536;          // 8,192,000

    prep_kernel <<<dim3(64),     256, 0, stream>>>(wqs, wvs, fcw, w1, w2,
                                                   wqT, wvT, fcwT, w1T, w2T);
    proj_kernel <<<dim3(250, 2), 256, 0, stream>>>(q, v, wqT, wvT, qh_bf, vhT);
    attn_kernel <<<dim3(256, 8), 256, 0, stream>>>(qh_bf, vhT, w1T, b1, w2T, b2, ctx);
    final_kernel<<<dim3(250),    256, 0, stream>>>(ctx, fcwT, q, lng, lnb, out);
}

// Round 5
// 257.042 us; speedup vs baseline: 2.7555x; 1.0321x over previous
//
#include <hip/hip_runtime.h>
#include <math.h>

#define B_   64
#define L_   500
#define F_   256
#define H_   4
#define DK   64

typedef unsigned short u16;
typedef unsigned int   u32;
typedef __attribute__((ext_vector_type(8))) short short8;
typedef __attribute__((ext_vector_type(4))) float f32x4;

static __device__ __forceinline__ u16 f2bf(float f) {
    u32 u = __float_as_uint(f);
    u32 r = (u + 0x7FFFu + ((u >> 16) & 1u)) >> 16;
    return (u16)r;
}

// ---------------------------------------------------------------------------
// Prep: bf16 transposed weights.
//  wqT/wvT/fcwT [256][256] ([n][k]); w1T[64][64]; w2T[512][64] (n>=500 -> 0)
// ---------------------------------------------------------------------------
__global__ __launch_bounds__(256) void prep_kernel(
    const float* __restrict__ wq, const float* __restrict__ wv,
    const float* __restrict__ fcw, const float* __restrict__ w1,
    const float* __restrict__ w2,
    u16* __restrict__ wqT, u16* __restrict__ wvT, u16* __restrict__ fcwT,
    u16* __restrict__ w1T, u16* __restrict__ w2T)
{
    int t = blockIdx.x * 256 + threadIdx.x;
    int stride = gridDim.x * 256;
    for (int i = t; i < 256 * 256; i += stride) {
        int n = i >> 8, k = i & 255;
        wqT[i]  = f2bf(wq[k * 256 + n]);
        wvT[i]  = f2bf(wv[k * 256 + n]);
        fcwT[i] = f2bf(fcw[k * 256 + n]);
    }
    for (int i = t; i < 64 * 64; i += stride) {
        int n = i >> 6, k = i & 63;
        w1T[i] = f2bf(w1[k * 64 + n]);
    }
    for (int i = t; i < 512 * 64; i += stride) {
        int n = i >> 6, k = i & 63;
        w2T[i] = f2bf(n < 500 ? w2[k * 500 + n] : 0.f);
    }
}

// ---------------------------------------------------------------------------
// Kernel 1: head projections, bf16 MFMA.
// grid (500, 2), block 512 = 8 waves in 2x4; block tile 64 rows x 256 cols.
// wave tile 32 x 64.  which=0: qh_bf [bh][500][64]; which=1: vhT [bh][64][512]
// ---------------------------------------------------------------------------
__global__ __launch_bounds__(512) void proj_kernel(
    const float* __restrict__ q, const float* __restrict__ v,
    const u16* __restrict__ wqT, const u16* __restrict__ wvT,
    u16* __restrict__ qh_bf, u16* __restrict__ vhT)
{
    const int which = blockIdx.y;
    const float* __restrict__ x = which ? v : q;
    const u16*   __restrict__ wT = which ? wvT : wqT;

    __shared__ u16 Xs[64][72];    // [m][k], pad 144 B
    __shared__ u16 Ws[256][72];   // [n][k], pad 144 B

    const int tid  = threadIdx.x;
    const int wvid = tid >> 6, ln = tid & 63;
    const int n16  = ln & 15, quad = ln >> 4;
    const int wr   = wvid >> 2, wc = wvid & 3;   // 2 x 4
    const int row0 = blockIdx.x * 64;

    f32x4 acc[2][4];
    #pragma unroll
    for (int mt = 0; mt < 2; mt++)
        #pragma unroll
        for (int nt = 0; nt < 4; nt++) acc[mt][nt] = (f32x4){0.f, 0.f, 0.f, 0.f};

    for (int kc = 0; kc < 256; kc += 64) {
        // stage X (fp32 -> bf16): 64 x 64
        #pragma unroll
        for (int j = 0; j < 2; j++) {
            int idx = tid + 512 * j;
            int m = idx >> 4, k4 = idx & 15;
            float4 a = *(const float4*)&x[(size_t)(row0 + m) * 256 + kc + k4 * 4];
            __align__(8) u16 t4[4] = {f2bf(a.x), f2bf(a.y), f2bf(a.z), f2bf(a.w)};
            *(uint2*)&Xs[m][k4 * 4] = *(const uint2*)t4;
        }
        // stage W^T: 256 x 64 bf16
        #pragma unroll
        for (int j = 0; j < 4; j++) {
            int idx = tid + 512 * j;
            int n = idx >> 3, k8 = idx & 7;
            *(uint4*)&Ws[n][k8 * 8] = *(const uint4*)&wT[n * 256 + kc + k8 * 8];
        }
        __syncthreads();
        #pragma unroll
        for (int ks = 0; ks < 2; ks++) {
            short8 af[2], bfr[4];
            #pragma unroll
            for (int mt = 0; mt < 2; mt++)
                af[mt] = *(const short8*)&Xs[wr * 32 + mt * 16 + n16][ks * 32 + quad * 8];
            #pragma unroll
            for (int nt = 0; nt < 4; nt++)
                bfr[nt] = *(const short8*)&Ws[wc * 64 + nt * 16 + n16][ks * 32 + quad * 8];
            #pragma unroll
            for (int mt = 0; mt < 2; mt++)
                #pragma unroll
                for (int nt = 0; nt < 4; nt++)
                    acc[mt][nt] = __builtin_amdgcn_mfma_f32_16x16x32_bf16(
                        af[mt], bfr[nt], acc[mt][nt], 0, 0, 0);
        }
        __syncthreads();
    }

    // h = wc (64-col groups), d = nt*16 + n16
    if (which == 0) {
        #pragma unroll
        for (int mt = 0; mt < 2; mt++) {
            int m0 = row0 + wr * 32 + mt * 16 + quad * 4;   // mult of 4
            int b  = m0 / 500;
            int l0 = m0 - 500 * b;                           // group never straddles b
            #pragma unroll
            for (int nt = 0; nt < 4; nt++) {
                int d = nt * 16 + n16;
                u16* dst = qh_bf + ((size_t)((b * 4 + wc) * 500 + l0)) * 64 + d;
                #pragma unroll
                for (int i = 0; i < 4; i++)
                    dst[(size_t)i * 64] = f2bf(acc[mt][nt][i]);
            }
        }
    } else {
        #pragma unroll
        for (int mt = 0; mt < 2; mt++) {
            int m0 = row0 + wr * 32 + mt * 16 + quad * 4;
            int b  = m0 / 500;
            int l0 = m0 - 500 * b;
            #pragma unroll
            for (int nt = 0; nt < 4; nt++) {
                int d = nt * 16 + n16;
                __align__(8) u16 t4[4];
                #pragma unroll
                for (int i = 0; i < 4; i++) t4[i] = f2bf(acc[mt][nt][i]);
                *(uint2*)&vhT[((size_t)((b * 4 + wc) * 64 + d)) * 512 + l0] =
                    *(const uint2*)t4;
            }
        }
    }
}

// ---------------------------------------------------------------------------
// Kernel 2: dense-synthesizer attention, bf16 MFMA.
// grid (256 bh, 8 row-chunks) so same-bh blocks land on the same XCD.
// LDS: one 36 KB union region (s_tmp | w2 double-buffer | v+p) -> 4 blk/CU.
// ---------------------------------------------------------------------------
__global__ __launch_bounds__(256) void attn_kernel(
    const u16* __restrict__ qh, const u16* __restrict__ vhT,
    const u16* __restrict__ w1T, const float* __restrict__ b1,
    const u16* __restrict__ w2T, const float* __restrict__ b2,
    u16* __restrict__ ctx)
{
    __shared__ __align__(16) char lds_raw[36864];
    u16 (*s_tmp)[16][72]  = (u16 (*)[16][72])  lds_raw;             // [4][16][72]
    u16 (*w2s)[128][72]   = (u16 (*)[128][72]) lds_raw;             // [2][128][72]
    u16 (*v_lds)[136]     = (u16 (*)[136])     lds_raw;             // [64][136]
    u16 (*p_lds)[16][136] = (u16 (*)[16][136]) (lds_raw + 17408);   // [4][16][136]

    const int tid  = threadIdx.x;
    const int wv   = tid >> 6;
    const int ln   = tid & 63;
    const int n16  = ln & 15;
    const int quad = ln >> 4;
    const int bh   = blockIdx.x;
    const int r0   = blockIdx.y * 64 + wv * 16;

    // ---- Phase A: s = relu(qh @ w1 + b1), C-layout -> LDS -> A-frag regs ----
    {
        const u16* qbase = qh + ((size_t)(bh * 500 + r0 + n16)) * 64;
        short8 a0 = *(const short8*)(qbase + quad * 8);
        short8 a1 = *(const short8*)(qbase + 32 + quad * 8);
        #pragma unroll
        for (int nt = 0; nt < 4; nt++) {
            const u16* wb = w1T + (nt * 16 + n16) * 64;
            short8 bb0 = *(const short8*)(wb + quad * 8);
            short8 bb1 = *(const short8*)(wb + 32 + quad * 8);
            f32x4 c = {0.f, 0.f, 0.f, 0.f};
            c = __builtin_amdgcn_mfma_f32_16x16x32_bf16(a0, bb0, c, 0, 0, 0);
            c = __builtin_amdgcn_mfma_f32_16x16x32_bf16(a1, bb1, c, 0, 0, 0);
            float bias = b1[nt * 16 + n16];
            #pragma unroll
            for (int i = 0; i < 4; i++)
                s_tmp[wv][quad * 4 + i][nt * 16 + n16] = f2bf(fmaxf(c[i] + bias, 0.f));
        }
    }
    __syncthreads();
    short8 sa0 = *(const short8*)&s_tmp[wv][n16][quad * 8];
    short8 sa1 = *(const short8*)&s_tmp[wv][n16][32 + quad * 8];
    __syncthreads();   // s_tmp region about to be reused for w2 staging

    // ---- Phase B: logits = s @ w2 + b2; w2T staged in LDS, double-buffered ----
    f32x4 acc[32];
    {
        // stage chunk 0
        #pragma unroll
        for (int j = 0; j < 4; j++) {
            int idx = tid + 256 * j;
            int n = idx >> 3, k8 = idx & 7;
            *(uint4*)&w2s[0][n][k8 * 8] = *(const uint4*)&w2T[n * 64 + k8 * 8];
        }
        __syncthreads();
        for (int cc = 0; cc < 4; cc++) {
            if (cc < 3) {
                const u16* src = w2T + (cc + 1) * 128 * 64;
                #pragma unroll
                for (int j = 0; j < 4; j++) {
                    int idx = tid + 256 * j;
                    int n = idx >> 3, k8 = idx & 7;
                    *(uint4*)&w2s[(cc + 1) & 1][n][k8 * 8] =
                        *(const uint4*)&src[n * 64 + k8 * 8];
                }
            }
            u16 (*buf)[72] = w2s[cc & 1];
            #pragma unroll
            for (int t = 0; t < 8; t++) {
                int nt = cc * 8 + t;
                short8 bb0 = *(const short8*)&buf[t * 16 + n16][quad * 8];
                short8 bb1 = *(const short8*)&buf[t * 16 + n16][32 + quad * 8];
                f32x4 c = {0.f, 0.f, 0.f, 0.f};
                c = __builtin_amdgcn_mfma_f32_16x16x32_bf16(sa0, bb0, c, 0, 0, 0);
                c = __builtin_amdgcn_mfma_f32_16x16x32_bf16(sa1, bb1, c, 0, 0, 0);
                int col = nt * 16 + n16;
                float bias = (col < 500) ? b2[col] : -INFINITY;
                #pragma unroll
                for (int i = 0; i < 4; i++) c[i] += bias;
                acc[nt] = c;
            }
            __syncthreads();
        }
    }

    // ---- softmax stats (P unnormalized; fold 1/sum into epilogue) ----
    float inv[4];
    {
        float mx[4], sm[4];
        #pragma unroll
        for (int i = 0; i < 4; i++) mx[i] = acc[0][i];
        #pragma unroll
        for (int nt = 1; nt < 32; nt++)
            #pragma unroll
            for (int i = 0; i < 4; i++) mx[i] = fmaxf(mx[i], acc[nt][i]);
        #pragma unroll
        for (int off = 1; off < 16; off <<= 1)
            #pragma unroll
            for (int i = 0; i < 4; i++) mx[i] = fmaxf(mx[i], __shfl_xor(mx[i], off));
        #pragma unroll
        for (int i = 0; i < 4; i++) sm[i] = 0.f;
        #pragma unroll
        for (int nt = 0; nt < 32; nt++)
            #pragma unroll
            for (int i = 0; i < 4; i++) {
                float e = __expf(acc[nt][i] - mx[i]);
                acc[nt][i] = e;
                sm[i] += e;
            }
        #pragma unroll
        for (int off = 1; off < 16; off <<= 1)
            #pragma unroll
            for (int i = 0; i < 4; i++) sm[i] += __shfl_xor(sm[i], off);
        #pragma unroll
        for (int i = 0; i < 4; i++) inv[i] = 1.f / sm[i];
    }

    // ---- Phase C: out = P @ vh in 4 K-chunks of 128 ----
    f32x4 oacc[4];
    #pragma unroll
    for (int nt = 0; nt < 4; nt++) oacc[nt] = (f32x4){0.f, 0.f, 0.f, 0.f};

    for (int cc = 0; cc < 4; cc++) {
        #pragma unroll
        for (int u = tid; u < 1024; u += 256) {
            int d  = u >> 4;
            int kk = (u & 15) * 8;
            *(short8*)&v_lds[d][kk] =
                *(const short8*)(vhT + ((size_t)(bh * 64 + d)) * 512 + cc * 128 + kk);
        }
        #pragma unroll
        for (int t = 0; t < 8; t++) {
            int nt = cc * 8 + t;
            int c  = t * 16 + n16;
            #pragma unroll
            for (int i = 0; i < 4; i++)
                p_lds[wv][quad * 4 + i][c] = f2bf(acc[nt][i]);
        }
        __syncthreads();
        #pragma unroll
        for (int ks = 0; ks < 4; ks++) {
            short8 pa = *(const short8*)&p_lds[wv][n16][ks * 32 + quad * 8];
            #pragma unroll
            for (int nt = 0; nt < 4; nt++) {
                short8 vb = *(const short8*)&v_lds[nt * 16 + n16][ks * 32 + quad * 8];
                oacc[nt] = __builtin_amdgcn_mfma_f32_16x16x32_bf16(pa, vb, oacc[nt], 0, 0, 0);
            }
        }
        __syncthreads();
    }

    // ---- epilogue: scale, write ctx bf16 ----
    {
        const int b = bh >> 2, h = bh & 3;
        #pragma unroll
        for (int i = 0; i < 4; i++) {
            int lrow = r0 + quad * 4 + i;
            if (lrow < 500) {
                float s = inv[i];
                u16* dst = &ctx[((size_t)(b * 500 + lrow)) * 256 + h * 64];
                #pragma unroll
                for (int nt = 0; nt < 4; nt++)
                    dst[nt * 16 + n16] = f2bf(oacc[nt][i] * s);
            }
        }
    }
}

// ---------------------------------------------------------------------------
// Kernel 3: out = LayerNorm(ctx @ fc_w + q), bf16 MFMA + fused LN epilogue.
// grid (500), block 512 = 8 waves in 2x4; block tile 64 rows x 256 cols.
// ---------------------------------------------------------------------------
__global__ __launch_bounds__(512) void final_kernel(
    const u16* __restrict__ ctx, const u16* __restrict__ fcwT,
    const float* __restrict__ qres, const float* __restrict__ g,
    const float* __restrict__ bta, float* __restrict__ out)
{
    __shared__ u16 Xs[64][72];
    __shared__ u16 Ws[256][72];
    __shared__ float red[4][2][64];   // [wc][s1|s2][row]
    __shared__ float murs[2][64];     // [mu|rs][row]

    const int tid  = threadIdx.x;
    const int wvid = tid >> 6, ln = tid & 63;
    const int n16  = ln & 15, quad = ln >> 4;
    const int wr   = wvid >> 2, wc = wvid & 3;   // 2 x 4
    const int row0 = blockIdx.x * 64;

    f32x4 acc[2][4];
    #pragma unroll
    for (int mt = 0; mt < 2; mt++)
        #pragma unroll
        for (int nt = 0; nt < 4; nt++) acc[mt][nt] = (f32x4){0.f, 0.f, 0.f, 0.f};

    for (int kc = 0; kc < 256; kc += 64) {
        // stage X: 64 x 64 bf16
        {
            int idx = tid;
            int m = idx >> 3, k8 = idx & 7;
            *(uint4*)&Xs[m][k8 * 8] =
                *(const uint4*)&ctx[(size_t)(row0 + m) * 256 + kc + k8 * 8];
        }
        // stage W^T: 256 x 64 bf16
        #pragma unroll
        for (int j = 0; j < 4; j++) {
            int idx = tid + 512 * j;
            int n = idx >> 3, k8 = idx & 7;
            *(uint4*)&Ws[n][k8 * 8] = *(const uint4*)&fcwT[n * 256 + kc + k8 * 8];
        }
        __syncthreads();
        #pragma unroll
        for (int ks = 0; ks < 2; ks++) {
            short8 af[2], bfr[4];
            #pragma unroll
            for (int mt = 0; mt < 2; mt++)
                af[mt] = *(const short8*)&Xs[wr * 32 + mt * 16 + n16][ks * 32 + quad * 8];
            #pragma unroll
            for (int nt = 0; nt < 4; nt++)
                bfr[nt] = *(const short8*)&Ws[wc * 64 + nt * 16 + n16][ks * 32 + quad * 8];
            #pragma unroll
            for (int mt = 0; mt < 2; mt++)
                #pragma unroll
                for (int nt = 0; nt < 4; nt++)
                    acc[mt][nt] = __builtin_amdgcn_mfma_f32_16x16x32_bf16(
                        af[mt], bfr[nt], acc[mt][nt], 0, 0, 0);
        }
        __syncthreads();
    }

    // residual add
    #pragma unroll
    for (int mt = 0; mt < 2; mt++) {
        int m0 = row0 + wr * 32 + mt * 16 + quad * 4;
        #pragma unroll
        for (int i = 0; i < 4; i++) {
            const float* rp = &qres[(size_t)(m0 + i) * 256 + wc * 64 + n16];
            #pragma unroll
            for (int nt = 0; nt < 4; nt++)
                acc[mt][nt][i] += rp[nt * 16];
        }
    }
    // per-row partial sums -> LDS
    #pragma unroll
    for (int mt = 0; mt < 2; mt++) {
        #pragma unroll
        for (int i = 0; i < 4; i++) {
            float s1 = 0.f, s2 = 0.f;
            #pragma unroll
            for (int nt = 0; nt < 4; nt++) {
                float vv = acc[mt][nt][i];
                s1 += vv; s2 += vv * vv;
            }
            #pragma unroll
            for (int off = 1; off < 16; off <<= 1) {
                s1 += __shfl_xor(s1, off);
                s2 += __shfl_xor(s2, off);
            }
            if (n16 == 0) {
                int r = wr * 32 + mt * 16 + quad * 4 + i;
                red[wc][0][r] = s1;
                red[wc][1][r] = s2;
            }
        }
    }
    __syncthreads();
    if (tid < 64) {
        float S1 = red[0][0][tid] + red[1][0][tid] + red[2][0][tid] + red[3][0][tid];
        float S2 = red[0][1][tid] + red[1][1][tid] + red[2][1][tid] + red[3][1][tid];
        float mu  = S1 * 0.00390625f;
        float var = S2 * 0.00390625f - mu * mu;
        murs[0][tid] = mu;
        murs[1][tid] = rsqrtf(var + 1e-6f);
    }
    __syncthreads();

    float gv[4], bv[4];
    #pragma unroll
    for (int nt = 0; nt < 4; nt++) {
        int col = wc * 64 + nt * 16 + n16;
        gv[nt] = g[col];
        bv[nt] = bta[col];
    }
    #pragma unroll
    for (int mt = 0; mt < 2; mt++) {
        int rb = wr * 32 + mt * 16 + quad * 4;
        #pragma unroll
        for (int i = 0; i < 4; i++) {
            float mu = murs[0][rb + i];
            float rs = murs[1][rb + i];
            float* op = &out[(size_t)(row0 + rb + i) * 256 + wc * 64 + n16];
            #pragma unroll
            for (int nt = 0; nt < 4; nt++)
                op[nt * 16] = (acc[mt][nt][i] - mu) * rs * gv[nt] + bv[nt];
        }
    }
}

// ---------------------------------------------------------------------------
extern "C" void kernel_launch(void* const* d_in, const int* in_sizes, int n_in,
                              void* d_out, int out_size, void* d_ws, size_t ws_size,
                              hipStream_t stream)
{
    const float* q   = (const float*)d_in[0];
    const float* v   = (const float*)d_in[2];
    const float* wqs = (const float*)d_in[3];
    const float* wvs = (const float*)d_in[4];
    const float* w1  = (const float*)d_in[5];
    const float* b1  = (const float*)d_in[6];
    const float* w2  = (const float*)d_in[7];
    const float* b2  = (const float*)d_in[8];
    const float* fcw = (const float*)d_in[9];
    const float* lng = (const float*)d_in[10];
    const float* lnb = (const float*)d_in[11];
    float* out = (float*)d_out;

    u16* qh_bf = (u16*)d_ws;            // 8,200,192 (padded: attn reads rows <512)
    u16* vhT   = qh_bf + 8200192;       // 8,388,608
    u16* w1T   = vhT + 8388608;         // 4,096
    u16* w2T   = w1T + 4096;            // 32,768
    u16* wqT   = w2T + 32768;           // 65,536
    u16* wvT   = wqT + 65536;           // 65,536
    u16* fcwT  = wvT + 65536;           // 65,536
    u16* ctx   = fcwT + 65536;          // 8,192,000

    prep_kernel <<<dim3(64),     256, 0, stream>>>(wqs, wvs, fcw, w1, w2,
                                                   wqT, wvT, fcwT, w1T, w2T);
    proj_kernel <<<dim3(500, 2), 512, 0, stream>>>(q, v, wqT, wvT, qh_bf, vhT);
    attn_kernel <<<dim3(256, 8), 256, 0, stream>>>(qh_bf, vhT, w1T, b1, w2T, b2, ctx);
    final_kernel<<<dim3(500),    512, 0, stream>>>(ctx, fcwT, q, lng, lnb, out);
}